// Round 9
// baseline (91.890 us; speedup 1.0000x reference)
//
#include <hip/hip_runtime.h>
#include <hip/hip_bf16.h>

// Problem constants (fixed by setup_inputs): C=64 cliques, S=16, D=256, P=65536
#define NC 64
#define NS 16
#define ND 256
#define NDP (ND + 4)   // padded LDS row: 260 floats. Column read xs[j][d] across
                       // j=0..15 hits bank (j*4+d)%32 -> 2-way alias = free (m136).
#define NP 65536
#define EPS 1e-8f

typedef float f4 __attribute__((ext_vector_type(4)));

// ---------------------------------------------------------------------------
// Fused kernel v3: v2 + MALL (Infinity Cache) partitioning.
//
// params is 268.435 MB = exactly the 256 MiB L3. A cyclic re-read (graph
// replays) of an exactly-capacity stream thrashes: R6 profile showed ~50%
// HBM miss. Fix: mark 1/8 of the params stream ((chunk&7)==7) non-temporal
// (no L3 allocate). The allocating subset (235 MB) then fits with headroom
// and stays L3-resident across replays; only the NT eighth + writes pay HBM.
//
// Stores stay non-temporal (write-once, must not evict params).
// ---------------------------------------------------------------------------
__global__ __launch_bounds__(256) void coexpert_fused(
    const float* __restrict__ reps,   // [C, S, D]
    const float* __restrict__ params, // [C, S, P]
    float* __restrict__ out)          // [C, S, P]
{
    const int chunk = blockIdx.x;     // 64 chunks of 1024 p's
    const int c     = blockIdx.y;     // 64 cliques
    const int t     = threadIdx.x;

    __shared__ float xs[NS][NDP];     // padded staged reps (~16.6 KiB)
    __shared__ float norms[NS];
    __shared__ float ws[NS][NS];

    // (1) Issue reps loads -> registers (4 x f4 per thread = 16 KiB/block).
    f4 xr[4];
    {
        const f4* xc = reinterpret_cast<const f4*>(reps + (size_t)c * NS * ND);
        #pragma unroll
        for (int m = 0; m < 4; ++m)
            xr[m] = xc[t + 256 * m];
    }

    // (2) Issue params loads. Cache partition: 7/8 of chunks allocate in
    //     L3 (and stay resident across replays); every 8th chunk streams
    //     non-temporally so the allocating set fits under 256 MiB.
    const size_t base = (size_t)c * NS * NP + (size_t)chunk * 1024 + (size_t)t * 4;
    const f4* pin  = reinterpret_cast<const f4*>(params + base);
    f4*       pout = reinterpret_cast<f4*>(out + base);

    f4 v[NS];
    if ((chunk & 7) != 7) {
        #pragma unroll
        for (int jj = 0; jj < NS; ++jj)
            v[jj] = pin[(size_t)jj * (NP / 4)];                       // allocate
    } else {
        #pragma unroll
        for (int jj = 0; jj < NS; ++jj)
            v[jj] = __builtin_nontemporal_load(pin + (size_t)jj * (NP / 4));
    }

    // (3) Prelude: stage reps, cosine-sim, row softmax.
    #pragma unroll
    for (int m = 0; m < 4; ++m) {
        const int q   = t + 256 * m;     // f4 index: 64 f4 per 256-float row
        const int row = q >> 6;
        const int col = (q & 63) << 2;
        *reinterpret_cast<f4*>(&xs[row][col]) = xr[m];
    }
    __syncthreads();

    const int i = t >> 4;
    const int j = t & 15;

    float dot = 0.f;
    #pragma unroll 8
    for (int d = 0; d < ND; d += 4) {
        f4 a = *reinterpret_cast<const f4*>(&xs[i][d]);   // 4-row broadcast
        f4 b = *reinterpret_cast<const f4*>(&xs[j][d]);   // 2-way alias (pad)
        dot += a.x * b.x + a.y * b.y + a.z * b.z + a.w * b.w;
    }

    if (i == j) norms[i] = sqrtf(dot);
    __syncthreads();

    float sim = dot / (norms[i] * norms[j] + EPS);

    // Row softmax over j: 16-lane-group butterfly (offsets 1,2,4,8 stay
    // in-group on wave64).
    float m_ = sim;
    #pragma unroll
    for (int off = 1; off < 16; off <<= 1)
        m_ = fmaxf(m_, __shfl_xor(m_, off));
    float e = expf(sim - m_);
    float s = e;
    #pragma unroll
    for (int off = 1; off < 16; off <<= 1)
        s += __shfl_xor(s, off);

    ws[i][j] = e / s;
    __syncthreads();

    // (4) Mix + non-temporal stores.
    #pragma unroll
    for (int ii = 0; ii < NS; ++ii) {
        f4 acc = (f4)(0.f);
        #pragma unroll
        for (int jj = 0; jj < NS; ++jj)
            acc += ws[ii][jj] * v[jj];   // LDS broadcast, conflict-free
        __builtin_nontemporal_store(acc, pout + (size_t)ii * (NP / 4));
    }
}

extern "C" void kernel_launch(void* const* d_in, const int* in_sizes, int n_in,
                              void* d_out, int out_size, void* d_ws, size_t ws_size,
                              hipStream_t stream) {
    const float* reps   = (const float*)d_in[0];   // [64,16,256]   f32
    const float* params = (const float*)d_in[1];   // [64,16,65536] f32
    float* out = (float*)d_out;                    // [64,16,65536] f32

    dim3 grid(NP / 1024, NC);                      // (64, 64)
    hipLaunchKernelGGL(coexpert_fused, grid, dim3(256), 0, stream,
                       reps, params, out);
}